// Round 1
// baseline (27.860 us; speedup 1.0000x reference)
//
#include <hip/hip_runtime.h>
#include <hip/hip_bf16.h>

typedef float f32x4 __attribute__((ext_vector_type(4)));

#define E_DIM 1024   // embed dim (output cols)
#define F_DIM 4096   // ffn dim
#define E_PER_BLOCK 16

// Kernel 1: o[e] = sum_g w_out[e,g] * relu( sum_f w2[g,f] * q[f] ),  e in [0,1024)
// q is the analytic 4-qubit circuit output from params (constant per launch).
__global__ __launch_bounds__(256) void qff_head(
    const float* __restrict__ w2,      // (4096, 4) row-major
    const float* __restrict__ wout,    // (1024, 4096) row-major
    const float* __restrict__ params,  // (4,)
    float* __restrict__ o)             // (1024,)
{
    __shared__ float h[F_DIM];

    // quantum circuit expvals (cheap, every thread computes)
    const float c0 = cosf(params[0]);
    const float c1 = cosf(params[1]);
    const float c2 = cosf(params[2]);
    const float c3 = cosf(params[3]);
    const float q0 = c1 * c2 * c3;
    const float q1 = c0 * c1;
    const float q2 = q1 * c2;
    const float q3 = q2 * c3;

    // h[g] = relu(w2[g,:] . q) — 16 per thread, float4 row reads
    const int t = threadIdx.x;
    const f32x4* w2v = reinterpret_cast<const f32x4*>(w2);
    for (int g = t; g < F_DIM; g += 256) {
        f32x4 w = w2v[g];
        float v = w.x * q0 + w.y * q1 + w.z * q2 + w.w * q3;
        h[g] = v > 0.0f ? v : 0.0f;
    }
    __syncthreads();

    // 4 waves per block; each wave produces one o[e] at a time via a
    // coalesced float4 dot over the 16 KB w_out row + shuffle reduce.
    const int wave = t >> 6;
    const int lane = t & 63;
    const int e0 = blockIdx.x * E_PER_BLOCK;
    const f32x4* h4 = reinterpret_cast<const f32x4*>(h);

    for (int i = wave; i < E_PER_BLOCK; i += 4) {
        const int e = e0 + i;
        const f32x4* wrow = reinterpret_cast<const f32x4*>(wout + (size_t)e * F_DIM);
        float s = 0.0f;
#pragma unroll
        for (int j = 0; j < F_DIM / 4 / 64; ++j) {   // 16 iterations
            f32x4 a = wrow[lane + j * 64];
            f32x4 b = h4[lane + j * 64];
            s += a.x * b.x + a.y * b.y + a.z * b.z + a.w * b.w;
        }
#pragma unroll
        for (int off = 32; off > 0; off >>= 1) s += __shfl_down(s, off);
        if (lane == 0) o[e] = s;
    }
}

// Kernel 2: out[r, :] = o[:] for all 16384 rows — pure streaming broadcast.
// Grid stride (blocks*256 float4s) is a multiple of 256 (= E_DIM/4), so each
// thread's source float4 is invariant: load once, stream nontemporal stores.
__global__ __launch_bounds__(256) void qff_bcast(
    const float* __restrict__ o, float* __restrict__ out, int n4)
{
    const f32x4* o4 = reinterpret_cast<const f32x4*>(o);
    f32x4* out4 = reinterpret_cast<f32x4*>(out);
    const int stride = gridDim.x * 256;                 // multiple of 256
    const int idx = blockIdx.x * 256 + threadIdx.x;
    const f32x4 v = o4[idx & (E_DIM / 4 - 1)];
    for (int i = idx; i < n4; i += stride) {
        __builtin_nontemporal_store(v, &out4[i]);
    }
}

extern "C" void kernel_launch(void* const* d_in, const int* in_sizes, int n_in,
                              void* d_out, int out_size, void* d_ws, size_t ws_size,
                              hipStream_t stream) {
    // inputs (setup_inputs order): x, w1, w2, w_out, params
    // x and w1 are a dead path (RZ on |0> is a global phase) — never read.
    const float* w2     = (const float*)d_in[2];
    const float* w_out  = (const float*)d_in[3];
    const float* params = (const float*)d_in[4];
    float* o   = (float*)d_ws;    // 1024 floats of scratch, rewritten every call
    float* out = (float*)d_out;

    qff_head<<<E_DIM / E_PER_BLOCK, 256, 0, stream>>>(w2, w_out, params, o);

    const int n4 = out_size / 4;  // 4,194,304 float4 stores = 64 MiB
    qff_bcast<<<2048, 256, 0, stream>>>(o, out, n4);
}

// Round 2
// 26.234 us; speedup vs baseline: 1.0620x; 1.0620x over previous
//
#include <hip/hip_runtime.h>
#include <hip/hip_bf16.h>

typedef float f32x4 __attribute__((ext_vector_type(4)));

#define E_DIM 1024   // embed dim (output cols)
#define F_DIM 4096   // ffn dim

// Kernel 1: o[e] = sum_g w_out[e,g] * relu( sum_f w2[g,f] * q[f] ),  e in [0,1024)
// q is the analytic 4-qubit circuit output from params (constant per launch).
// 256 blocks x 256 threads; one output element per wave (4 per block).
__global__ __launch_bounds__(256) void qff_head(
    const float* __restrict__ w2,      // (4096, 4) row-major
    const float* __restrict__ wout,    // (1024, 4096) row-major
    const float* __restrict__ params,  // (4,)
    float* __restrict__ o)             // (1024,)
{
    __shared__ float h[F_DIM];

    // quantum circuit expvals (cheap, every thread computes)
    const float c0 = cosf(params[0]);
    const float c1 = cosf(params[1]);
    const float c2 = cosf(params[2]);
    const float c3 = cosf(params[3]);
    const float q0 = c1 * c2 * c3;
    const float q1 = c0 * c1;
    const float q2 = q1 * c2;
    const float q3 = q2 * c3;

    // h[g] = relu(w2[g,:] . q) — 16 per thread, float4 row reads (w2 is 64 KB,
    // L2-resident after the first block on each XCD)
    const int t = threadIdx.x;
    const f32x4* w2v = reinterpret_cast<const f32x4*>(w2);
    for (int g = t; g < F_DIM; g += 256) {
        f32x4 w = w2v[g];
        float v = w.x * q0 + w.y * q1 + w.z * q2 + w.w * q3;
        h[g] = v > 0.0f ? v : 0.0f;
    }
    __syncthreads();

    // one e per wave: coalesced float4 dot over the 16 KB w_out row + reduce
    const int wave = t >> 6;
    const int lane = t & 63;
    const int e = blockIdx.x * 4 + wave;
    const f32x4* h4 = reinterpret_cast<const f32x4*>(h);
    const f32x4* wrow = reinterpret_cast<const f32x4*>(wout + (size_t)e * F_DIM);

    float s = 0.0f;
#pragma unroll
    for (int j = 0; j < F_DIM / 4 / 64; ++j) {   // 16 iterations
        f32x4 a = wrow[lane + j * 64];
        f32x4 b = h4[lane + j * 64];
        s += a.x * b.x + a.y * b.y + a.z * b.z + a.w * b.w;
    }
#pragma unroll
    for (int off = 32; off > 0; off >>= 1) s += __shfl_down(s, off);
    if (lane == 0) o[e] = s;
}

// Kernel 2: out[r, :] = o[:] for all 16384 rows — pure streaming broadcast.
// Grid stride (blocks*256 float4s) is a multiple of 256 (= E_DIM/4), so each
// thread's source float4 is invariant: load once, stream nontemporal stores.
__global__ __launch_bounds__(256) void qff_bcast(
    const float* __restrict__ o, float* __restrict__ out, int n4)
{
    const f32x4* o4 = reinterpret_cast<const f32x4*>(o);
    f32x4* out4 = reinterpret_cast<f32x4*>(out);
    const int stride = gridDim.x * 256;                 // multiple of 256
    const int idx = blockIdx.x * 256 + threadIdx.x;
    const f32x4 v = o4[idx & (E_DIM / 4 - 1)];
    for (int i = idx; i < n4; i += stride) {
        __builtin_nontemporal_store(v, &out4[i]);
    }
}

extern "C" void kernel_launch(void* const* d_in, const int* in_sizes, int n_in,
                              void* d_out, int out_size, void* d_ws, size_t ws_size,
                              hipStream_t stream) {
    // inputs (setup_inputs order): x, w1, w2, w_out, params
    // x and w1 are a dead path (RZ on |0> is a global phase) — never read.
    const float* w2     = (const float*)d_in[2];
    const float* w_out  = (const float*)d_in[3];
    const float* params = (const float*)d_in[4];
    float* o   = (float*)d_ws;    // 1024 floats of scratch, rewritten every call
    float* out = (float*)d_out;

    qff_head<<<E_DIM / 4, 256, 0, stream>>>(w2, w_out, params, o);

    const int n4 = out_size / 4;  // 4,194,304 float4 stores = 64 MiB
    qff_bcast<<<2048, 256, 0, stream>>>(o, out, n4);
}